// Round 4
// baseline (24714.096 us; speedup 1.0000x reference)
//
#include <hip/hip_runtime.h>
#include <math.h>

#define SEQ 8192
#define IN_DIM 128
#define HID 512
#define OUT_DIM 128
#define NK 9      // 8 spline basis + 1 silu slot
#define KNOTS 12

// ws layout (floats). W9HU region is reused for W9O by build2 (after seq).
#define WS_W9HU  0                               // 128*9*512   = 589,824 (xpart); later W9O 512*9*128 (same size)
#define WS_W9R8  589824                          // 512*8*64*8  = 2,097,152 (seq spline w)
#define WS_W9RS  (WS_W9R8 + 2097152)             // 512*8*64    = 262,144  (seq silu w)
#define WS_XPART (WS_W9RS + 262144)              // 8192*512    = 4,194,304
#define WS_HCOMM (WS_XPART + 4194304)            // 8192*512    = 4,194,304
#define WS_TOTAL (WS_HCOMM + 4194304)            // 11,337,728 floats = 45.4 MB

#define SENTINEL 0x7FA0DEADu   // sNaN payload; never produced by arithmetic

#define NWG 64
#define TPB2 512

// ---- closed-form uniform cubic B-spline basis + silu, written to a 12-float LDS row ----
// Row r lives at bas[3r..3r+2] (float4); [0..7]=B_j, [8]=silu, [9..11]=pad.
__device__ __forceinline__ void write_basis_row(float x, float g0, float inv_h,
                                                float4* bas, int row) {
    float* rowp = (float*)&bas[row*3];
    float tq = (x - g0) * inv_h;
    float cf = floorf(tq);
    float u  = tq - cf;
    int   c  = (int)cf;
    float si = x * __builtin_amdgcn_rcpf(1.0f + __expf(-x));
    ((float4*)rowp)[0] = make_float4(0.f, 0.f, 0.f, 0.f);
    ((float4*)rowp)[1] = make_float4(0.f, 0.f, 0.f, 0.f);
    ((float4*)rowp)[2] = make_float4(si, 0.f, 0.f, 0.f);
    if (c >= 0 && c <= 10) {
        float um = 1.0f - u;
        float u2 = u*u, u3 = u2*u;
        float w0 = um*um*um*(1.0f/6.0f);
        float w1 = 0.5f*u3 - u2 + (2.0f/3.0f);
        float w2 = -0.5f*u3 + 0.5f*u2 + 0.5f*u + (1.0f/6.0f);
        float w3 = u3*(1.0f/6.0f);
        int j0 = c - 3;
        if (j0     >= 0) rowp[j0]     = w0;   // j0   <= 7 since c <= 10
        if (j0 + 1 >= 0 && j0 + 1 <= 7) rowp[j0 + 1] = w1;
        if (j0 + 2 >= 0 && j0 + 2 <= 7) rowp[j0 + 2] = w2;
        if (j0 + 3 <= 7) rowp[j0 + 3] = w3;   // j0+3 = c >= 0
    }
}

// ---------------- build1: xpart weights + seq weights + sentinel fill ----------------
__global__ __launch_bounds__(256) void build1_kernel(
    const float* __restrict__ hu_coef, const float* __restrict__ hu_sb, const float* __restrict__ hu_ssp,
    float* __restrict__ ws)
{
    int idx = blockIdx.x * blockDim.x + threadIdx.x;
    int stride = gridDim.x * blockDim.x;
    // xpart slab: [i<128][k<9][o<512]
    const int N1 = 128 * 9 * 512;
    for (int p = idx; p < N1; p += stride) {
        int o = p & 511; int k = (p >> 9) % 9; int i = p / 4608;
        float v = (k < 8) ? hu_ssp[i*HID + o] * hu_coef[(i*HID + o)*8 + k] : hu_sb[i*HID + o];
        ws[WS_W9HU + p] = v;
    }
    // seq spline slab: [o<512][ci<8][l<64][k<8], input gi = 128 + 64*ci + l
    const int N2 = 512 * 8 * 64 * 8;
    for (int q = idx; q < N2; q += stride) {
        int k = q & 7; int l = (q >> 3) & 63; int ci = (q >> 9) & 7; int o = q >> 12;
        int gi = IN_DIM + 64*ci + l;
        ws[WS_W9R8 + q] = hu_ssp[gi*HID + o] * hu_coef[(gi*HID + o)*8 + k];
    }
    // seq silu slab: [o<512][ci<8][l<64]
    const int N3 = 512 * 8 * 64;
    for (int r = idx; r < N3; r += stride) {
        int l = r & 63; int ci = (r >> 6) & 7; int o = r >> 9;
        int gi = IN_DIM + 64*ci + l;
        ws[WS_W9RS + r] = hu_sb[gi*HID + o];
    }
    // sentinel fill
    unsigned* hc = (unsigned*)(ws + WS_HCOMM);
    for (int p = idx; p < SEQ*HID; p += stride) hc[p] = SENTINEL;
}

// ---------------- build2: output-layer weights (overlays W9HU region; runs after seq) ----------------
__global__ __launch_bounds__(256) void build2_kernel(
    const float* __restrict__ out_coef, const float* __restrict__ out_sb, const float* __restrict__ out_ssp,
    float* __restrict__ ws)
{
    int idx = blockIdx.x * blockDim.x + threadIdx.x;
    int stride = gridDim.x * blockDim.x;
    const int N = 512 * 9 * 128;   // [i<512][k<9][o<128]
    for (int p = idx; p < N; p += stride) {
        int o = p & 127; int k = (p >> 7) % 9; int i = p / 1152;
        float v = (k < 8) ? out_ssp[i*OUT_DIM + o] * out_coef[(i*OUT_DIM + o)*8 + k] : out_sb[i*OUT_DIM + o];
        ws[WS_W9HU + p] = v;
    }
}

// ---------------- phase 1: x-part contributions (parallel) ----------------
#define R1 4
__global__ __launch_bounds__(256) void xpart_kernel(
    const float* __restrict__ X, const float* __restrict__ hu_grid, float* __restrict__ ws)
{
    const int tid = threadIdx.x;
    const int t0 = blockIdx.x * R1;
    const float* W9 = ws + WS_W9HU;
    float* xpart = ws + WS_XPART;
    float g0 = hu_grid[0];
    float inv_h = 1.0f / (hu_grid[1] - hu_grid[0]);

    __shared__ float4 bas[R1*IN_DIM*3];
    #pragma unroll
    for (int rep = 0; rep < 2; ++rep) {
        int idx = tid + rep*256;
        int r = idx >> 7, i = idx & 127;
        write_basis_row(X[(t0 + r)*IN_DIM + i], g0, inv_h, bas, idx);
    }
    __syncthreads();

    float acc[R1][2];
    #pragma unroll
    for (int r = 0; r < R1; ++r) { acc[r][0] = 0.f; acc[r][1] = 0.f; }

    for (int i = 0; i < IN_DIM; ++i) {
        float w1[9], w2[9];
        #pragma unroll
        for (int k = 0; k < 9; ++k) {
            w1[k] = W9[(i*NK+k)*HID + tid];
            w2[k] = W9[(i*NK+k)*HID + tid + 256];
        }
        #pragma unroll
        for (int r = 0; r < R1; ++r) {
            const float* rp = (const float*)&bas[(r*IN_DIM + i)*3];
            float4 b0 = ((const float4*)rp)[0], b1 = ((const float4*)rp)[1];
            float b8 = rp[8];
            float s1 = w1[0]*b0.x + w1[1]*b0.y + w1[2]*b0.z + w1[3]*b0.w
                     + w1[4]*b1.x + w1[5]*b1.y + w1[6]*b1.z + w1[7]*b1.w + w1[8]*b8;
            float s2 = w2[0]*b0.x + w2[1]*b0.y + w2[2]*b0.z + w2[3]*b0.w
                     + w2[4]*b1.x + w2[5]*b1.y + w2[6]*b1.z + w2[7]*b1.w + w2[8]*b8;
            acc[r][0] += s1; acc[r][1] += s2;
        }
    }
    #pragma unroll
    for (int r = 0; r < R1; ++r) {
        xpart[(t0+r)*HID + tid]       = acc[r][0];
        xpart[(t0+r)*HID + tid + 256] = acc[r][1];
    }
}

// ---------------- phase 2: sequential recurrence (wave-per-output, agent-atomic relay) ----------------
__global__ __launch_bounds__(TPB2) void seq_kernel(
    const float* __restrict__ h0, const float* __restrict__ hu_grid,
    float* __restrict__ ws, float* __restrict__ d_out)
{
    const int tid  = threadIdx.x;
    const int lane = tid & 63;
    const int wave = tid >> 6;
    const int o    = blockIdx.x * 8 + wave;     // this wave's output
    const float* W8 = ws + WS_W9R8;
    const float* Wsl = ws + WS_W9RS;
    const float* xpart = ws + WS_XPART;
    float* hcomm = ws + WS_HCOMM;
    float* hs_out = d_out + SEQ*OUT_DIM;
    float g0 = hu_grid[0];
    float inv_h = 1.0f / (hu_grid[1] - hu_grid[0]);

    // register-resident weights: lane covers h-inputs i_h = lane + 64*ci
    float w[8][9];
    #pragma unroll
    for (int ci = 0; ci < 8; ++ci) {
        const float* base = W8 + (((size_t)o*8 + ci)*64 + lane)*8;
        float4 A = ((const float4*)base)[0];
        float4 B = ((const float4*)base)[1];
        w[ci][0]=A.x; w[ci][1]=A.y; w[ci][2]=A.z; w[ci][3]=A.w;
        w[ci][4]=B.x; w[ci][5]=B.y; w[ci][6]=B.z; w[ci][7]=B.w;
        w[ci][8] = Wsl[((size_t)o*8 + ci)*64 + lane];
    }

    __shared__ float4 bas[HID*3];

    for (int t = 0; t < SEQ; ++t) {
        float xf = (lane == 0) ? xpart[t*HID + o] : 0.0f;  // poll-independent prefetch

        float hv;
        if (t == 0) {
            hv = h0[tid];
        } else {
            const unsigned* pp = (const unsigned*)&hcomm[(size_t)(t-1)*HID + tid];
            unsigned u = __hip_atomic_load(pp, __ATOMIC_RELAXED, __HIP_MEMORY_SCOPE_AGENT);
            int sp = 0;
            while (u == SENTINEL && ++sp < (1 << 24))
                u = __hip_atomic_load(pp, __ATOMIC_RELAXED, __HIP_MEMORY_SCOPE_AGENT);
            hv = __uint_as_float(u);
        }

        write_basis_row(hv, g0, inv_h, bas, tid);
        __syncthreads();

        float a0 = 0.f, a1 = 0.f, a2 = 0.f, a3 = 0.f;
        #pragma unroll
        for (int ci = 0; ci < 8; ++ci) {
            const float* rp = (const float*)&bas[(lane + (ci << 6))*3];
            float4 b0 = ((const float4*)rp)[0], b1 = ((const float4*)rp)[1];
            float b8 = rp[8];
            float s = w[ci][0]*b0.x + w[ci][1]*b0.y + w[ci][2]*b0.z + w[ci][3]*b0.w
                    + w[ci][4]*b1.x + w[ci][5]*b1.y + w[ci][6]*b1.z + w[ci][7]*b1.w
                    + w[ci][8]*b8;
            if      ((ci & 3) == 0) a0 += s;
            else if ((ci & 3) == 1) a1 += s;
            else if ((ci & 3) == 2) a2 += s;
            else                    a3 += s;
        }
        float acc = (a0 + a1) + (a2 + a3);
        acc += __shfl_xor(acc, 1, 64);
        acc += __shfl_xor(acc, 2, 64);
        acc += __shfl_xor(acc, 4, 64);
        acc += __shfl_xor(acc, 8, 64);
        acc += __shfl_xor(acc, 16, 64);
        acc += __shfl_xor(acc, 32, 64);
        if (lane == 0) {
            float s = acc + xf;
            __hip_atomic_store((unsigned*)&hcomm[(size_t)t*HID + o], __float_as_uint(s),
                               __ATOMIC_RELAXED, __HIP_MEMORY_SCOPE_AGENT);
            hs_out[(size_t)t*HID + o] = s;   // plain store, off critical path
        }
        __syncthreads();   // WAR: bas rows rewritten next step
    }
}

// ---------------- phase 3: output layer (parallel) ----------------
#define R3 2
__global__ __launch_bounds__(256) void outlayer_kernel(
    const float* __restrict__ out_grid, float* __restrict__ ws, float* __restrict__ d_out)
{
    const int tid = threadIdx.x;
    const int t0 = blockIdx.x * R3;
    const float* W9o = ws + WS_W9HU;   // overlaid by build2
    const float* hs = d_out + SEQ*OUT_DIM;
    float g0 = out_grid[0];
    float inv_h = 1.0f / (out_grid[1] - out_grid[0]);

    __shared__ float4 bas[R3*HID*3];
    #pragma unroll
    for (int rep = 0; rep < 4; ++rep) {
        int idx = tid + rep*256;
        int r = idx >> 9, i = idx & 511;
        write_basis_row(hs[(size_t)(t0+r)*HID + i], g0, inv_h, bas, idx);
    }
    __syncthreads();

    const int oo = tid & 127;
    const int half = tid >> 7;
    float acc[R3] = {0.f, 0.f};
    for (int ii = 0; ii < 256; ++ii) {
        int i = half*256 + ii;
        float wv[9];
        #pragma unroll
        for (int k = 0; k < 9; ++k) wv[k] = W9o[(i*NK+k)*OUT_DIM + oo];
        #pragma unroll
        for (int r = 0; r < R3; ++r) {
            const float* rp = (const float*)&bas[(r*HID + i)*3];
            float4 b0 = ((const float4*)rp)[0], b1 = ((const float4*)rp)[1];
            float b8 = rp[8];
            acc[r] += wv[0]*b0.x + wv[1]*b0.y + wv[2]*b0.z + wv[3]*b0.w
                    + wv[4]*b1.x + wv[5]*b1.y + wv[6]*b1.z + wv[7]*b1.w + wv[8]*b8;
        }
    }
    __shared__ float red[2][R3][128];
    red[half][0][oo] = acc[0];
    red[half][1][oo] = acc[1];
    __syncthreads();
    {
        int rr = tid >> 7, o2 = tid & 127;
        d_out[(size_t)(t0+rr)*OUT_DIM + o2] = red[0][rr][o2] + red[1][rr][o2];
    }
}

extern "C" void kernel_launch(void* const* d_in, const int* in_sizes, int n_in,
                              void* d_out, int out_size, void* d_ws, size_t ws_size,
                              hipStream_t stream) {
    (void)in_sizes; (void)n_in; (void)out_size; (void)ws_size;
    const float* X        = (const float*)d_in[0];
    const float* h0       = (const float*)d_in[1];
    const float* hu_grid  = (const float*)d_in[2];
    const float* hu_coef  = (const float*)d_in[3];
    const float* hu_sb    = (const float*)d_in[4];
    const float* hu_ssp   = (const float*)d_in[5];
    const float* out_grid = (const float*)d_in[6];
    const float* out_coef = (const float*)d_in[7];
    const float* out_sb   = (const float*)d_in[8];
    const float* out_ssp  = (const float*)d_in[9];
    float* out = (float*)d_out;
    float* ws  = (float*)d_ws;

    hipLaunchKernelGGL(build1_kernel, dim3(2048), dim3(256), 0, stream,
                       hu_coef, hu_sb, hu_ssp, ws);
    hipLaunchKernelGGL(xpart_kernel, dim3(SEQ/R1), dim3(256), 0, stream, X, hu_grid, ws);
    hipLaunchKernelGGL(seq_kernel, dim3(NWG), dim3(TPB2), 0, stream, h0, hu_grid, ws, out);
    hipLaunchKernelGGL(build2_kernel, dim3(1024), dim3(256), 0, stream,
                       out_coef, out_sb, out_ssp, ws);
    hipLaunchKernelGGL(outlayer_kernel, dim3(SEQ/R3), dim3(256), 0, stream, out_grid, ws, out);
}